// Round 9
// baseline (257.410 us; speedup 1.0000x reference)
//
#include <hip/hip_runtime.h>
#include <math.h>
#include <float.h>

typedef __attribute__((ext_vector_type(4))) float f32x4;
typedef __attribute__((ext_vector_type(8))) __bf16 bf16x8;
typedef __attribute__((ext_vector_type(4))) __bf16 bf16x4;

#define NEG_TOPK 10
#define MT 128        // output cols per block
#define BK 64         // K-step
#define SIMSTR 136    // ushort stride for sims rows (272 B, 16B-aligned)
#define ABYTES 32768  // A tile: 256 rows x 128 B bf16
#define BBYTES 16384  // B tile: 128 rows x 128 B bf16
#define TBUF (ABYTES + BBYTES)   // 49152 per buffer; x2 = 96 KB -> 1 block/CU

// Branchless static-index top-k insert (sorted descending); pure VGPRs.
__device__ __forceinline__ void topk_ins(float (&top)[NEG_TOPK], float v) {
    #pragma unroll
    for (int q = NEG_TOPK - 1; q >= 1; --q)
        top[q] = fmaxf(fminf(v, top[q - 1]), top[q]);
    top[0] = fmaxf(top[0], v);
}

__device__ __forceinline__ bf16x4 cvt4(float4 v) {
    bf16x4 r;
    r[0] = (__bf16)v.x; r[1] = (__bf16)v.y;
    r[2] = (__bf16)v.z; r[3] = (__bf16)v.w;
    return r;
}

// Pass 0: convert A (fp32 [256][512]) -> bf16 in the INVERSE-SWIZZLED layout
// so pass1's linear global_load_lds reproduces the swizzled LDS image:
//   image[r*128 + ((g*8) ^ ((r&7)<<4))] = bf16x4(A[r][step*64 + g*4 ..])
__global__ __launch_bounds__(256) void cl_pass0(
    const float* __restrict__ A, char* __restrict__ A_swz, int D)
{
    const int idx = blockIdx.x * 256 + threadIdx.x;   // 32768 granules
    const int r    = idx >> 7;        // 0..255
    const int rem  = idx & 127;       // granule within row (8B = 4 bf16)
    const int step = rem >> 4;        // 0..7
    const int g    = rem & 15;        // 0..15
    float4 v = ((const float4*)A)[r * (D >> 2) + rem];
    bf16x4 b = cvt4(v);
    const int off = step * ABYTES + r * 128 + ((g * 8) ^ ((r & 7) << 4));
    *(unsigned long long*)(A_swz + off) = *(unsigned long long*)&b;
}

// Pass 1: bf16 MFMA GEMM, 256x128 block tile, 8 waves (4x2) of 64x64
// wave-tiles, phase-split schedule (2 phases/K-step, setprio'd MFMA
// clusters, counted vmcnt at tile boundary). A via global_load_lds from
// pre-swizzled bf16; B reg-staged 2 tiles deep (static even/odd sets).
__global__ __launch_bounds__(512, 2) void cl_pass1(
    const char* __restrict__ A_swz, // [8][32768] pre-swizzled bf16 A tiles
    const float* __restrict__ Bm,   // [M, D]  inputs_row fp32
    const int* __restrict__ tcol,   // [256]
    const int* __restrict__ trow,   // [M]
    float* __restrict__ part_topk,  // [256, nch, 10]   nch = 2*gridDim.x
    float* __restrict__ pos_part,   // [256, nch]
    int D)
{
    __shared__ char smem[2 * TBUF];  // 96 KB -> 1 block/CU

    const int mb = blockIdx.x;
    const int j0 = mb * MT;
    const int t  = threadIdx.x;
    const int wave = t >> 6, lane = t & 63;
    const int wr = wave >> 1, wc = wave & 1;   // 4x2 waves; wave tile 64x64
    const int lrow = lane & 15, lk = lane >> 4;

    const float4* B4 = (const float4*)Bm;
    const int ldq = D >> 2;          // float4 per row
    const int NSTEP = D / BK;        // 8

    // B staging: 128 rows x 16 f4 per step; thread -> row t>>2, 4 f4 slots
    const int rB = t >> 2;
    const int cB = t & 3;

    f32x4 acc[4][4];
    #pragma unroll
    for (int m = 0; m < 4; ++m)
        #pragma unroll
        for (int n = 0; n < 4; ++n)
            acc[m][n] = (f32x4){0.f, 0.f, 0.f, 0.f};

    float4 b0[4], b1[4];             // B prefetch sets, statically named

    const char* gA = A_swz + wave * 4096 + lane * 16;
    char* buf0 = smem;
    char* buf1 = smem + TBUF;

    const int swz = (lrow & 7) << 4;
    const int bswzr = (rB & 7) << 4;

#define LOAD_B(STEP, SET)                                                      \
    {                                                                          \
        const int kq_ = (STEP) * (BK / 4);                                     \
        _Pragma("unroll")                                                      \
        for (int s = 0; s < 4; ++s)                                            \
            SET[s] = B4[(size_t)(j0 + rB) * ldq + kq_ + cB + 4 * s];           \
    }

#define STAGE_B(BUFP, SET)                                                     \
    {                                                                          \
        char* Bb_ = (BUFP) + ABYTES;                                           \
        _Pragma("unroll")                                                      \
        for (int s = 0; s < 4; ++s)                                            \
            *(bf16x4*)(Bb_ + rB * 128 + (((cB + 4 * s) * 8) ^ bswzr)) =        \
                cvt4(SET[s]);                                                  \
    }

#define GLDS_A(STEP, BUFP)                                                     \
    {                                                                          \
        const char* gp_ = gA + (STEP) * ABYTES;                                \
        char* lp_ = (BUFP) + wave * 4096;                                      \
        _Pragma("unroll")                                                      \
        for (int q = 0; q < 4; ++q)                                            \
            __builtin_amdgcn_global_load_lds(                                  \
                (const __attribute__((address_space(1))) void*)(gp_ + q*1024), \
                (__attribute__((address_space(3))) void*)(lp_ + q*1024),       \
                16, 0, 0);                                                     \
    }

#define DS_FRAGS(BUFP, KB, AF, BF)                                             \
    _Pragma("unroll")                                                          \
    for (int m = 0; m < 4; ++m)                                                \
        AF[m] = *(const bf16x8*)((BUFP) + (wr * 64 + m * 16 + lrow) * 128      \
                                 + (((KB) + lk * 16) ^ swz));                  \
    _Pragma("unroll")                                                          \
    for (int n = 0; n < 4; ++n)                                                \
        BF[n] = *(const bf16x8*)((BUFP) + ABYTES                               \
                                 + (wc * 64 + n * 16 + lrow) * 128             \
                                 + (((KB) + lk * 16) ^ swz));

#define MFMA16(AF, BF)                                                         \
    __builtin_amdgcn_s_setprio(1);                                             \
    _Pragma("unroll")                                                          \
    for (int m = 0; m < 4; ++m)                                                \
        _Pragma("unroll")                                                      \
        for (int n = 0; n < 4; ++n)                                            \
            acc[m][n] = __builtin_amdgcn_mfma_f32_16x16x32_bf16(               \
                AF[m], BF[n], acc[m][n], 0, 0, 0);                             \
    __builtin_amdgcn_s_setprio(0);

// One K-tile, two phases. CURB/NXTB: current/next LDS buffer. WSET: B regs
// for tile T+1 (ds_written this tile). LSET: B regs receiving tile T+2.
// Boundary wait: queue = [glds(T+1) x4 (issued P0), LSET x4 (issued P1)]
// -> vmcnt(4) drains exactly the glds; vmcnt(0) when LSET wasn't issued.
#define TILE(T, CURB, NXTB, WSET, LSET)                                        \
    {   /* ---- phase 0: ks=0 ---- */                                          \
        bf16x8 af0[4], bf0[4];                                                 \
        DS_FRAGS(CURB, 0, af0, bf0);                                           \
        if ((T) + 1 < NSTEP) GLDS_A((T) + 1, NXTB);                            \
        MFMA16(af0, bf0);                                                      \
        __builtin_amdgcn_s_barrier();                                          \
    }                                                                          \
    {   /* ---- phase 1: ks=1 + staging + boundary ---- */                     \
        bf16x8 af1[4], bf1[4];                                                 \
        DS_FRAGS(CURB, 64, af1, bf1);                                          \
        if ((T) + 1 < NSTEP) STAGE_B(NXTB, WSET);                              \
        if ((T) + 2 < NSTEP) LOAD_B((T) + 2, LSET);                            \
        MFMA16(af1, bf1);                                                      \
        __builtin_amdgcn_sched_barrier(0);                                     \
        if ((T) + 2 < NSTEP) {                                                 \
            asm volatile("s_waitcnt vmcnt(4) lgkmcnt(0)" ::: "memory");        \
        } else {                                                               \
            asm volatile("s_waitcnt vmcnt(0) lgkmcnt(0)" ::: "memory");        \
        }                                                                      \
        __builtin_amdgcn_s_barrier();                                          \
        __builtin_amdgcn_sched_barrier(0);                                     \
    }

    // ---- prologue: tile0 A + B(0), B(1); stage B(0); full drain (once)
    GLDS_A(0, buf0);
    LOAD_B(0, b0);
    LOAD_B(1, b1);
    STAGE_B(buf0, b0);
    asm volatile("s_waitcnt vmcnt(0) lgkmcnt(0)" ::: "memory");
    __builtin_amdgcn_s_barrier();
    __builtin_amdgcn_sched_barrier(0);

    // ---- main loop: even tile uses buf0 (stage B from b1, load into b0),
    //                 odd tile uses buf1 (stage from b0, load into b1).
    for (int tt = 0; tt < NSTEP; tt += 2) {
        TILE(tt,     buf0, buf1, b1, b0)
        TILE(tt + 1, buf1, buf0, b0, b1)
    }

    // ---- epilogue: sims (bf16 [256][136]) into smem (all tiles done)
    unsigned short* simsb = (unsigned short*)smem;
    #pragma unroll
    for (int m = 0; m < 4; ++m)
        #pragma unroll
        for (int n = 0; n < 4; ++n)
            #pragma unroll
            for (int r = 0; r < 4; ++r) {
                int row = wr * 64 + m * 16 + lk * 4 + r;
                int col = wc * 64 + n * 16 + lrow;
                __bf16 b = (__bf16)acc[m][n][r];
                simsb[row * SIMSTR + col] = *(unsigned short*)&b;
            }
    __syncthreads();

    // fused scan: 2 threads per row, 64 cols each; labels from global
    {
        const int row = t >> 1, half = t & 1;
        const int myc = tcol[row];
        const int4* lab4 = (const int4*)(trow + j0 + half * 64);
        float top[NEG_TOPK];
        #pragma unroll
        for (int q = 0; q < NEG_TOPK; ++q) top[q] = -INFINITY;
        float pos = 0.f;
        #pragma unroll
        for (int j = 0; j < 8; ++j) {
            bf16x8 v8 = *(const bf16x8*)(&simsb[row * SIMSTR + half * 64 + j * 8]);
            int4 l1 = lab4[2 * j], l2 = lab4[2 * j + 1];
            int lab[8] = {l1.x, l1.y, l1.z, l1.w, l2.x, l2.y, l2.z, l2.w};
            #pragma unroll
            for (int e = 0; e < 8; ++e) {
                float s = (float)v8[e];
                bool same = (lab[e] == myc);
                pos += (same && s < 0.99999f) ? (1.f - s) : 0.f;
                topk_ins(top, same ? -INFINITY : s);
            }
        }
        const int nch = 2 * gridDim.x;       // 1024 chunks of 64 cols
        const int ch = mb * 2 + half;
        float* dst = part_topk + ((size_t)row * nch + ch) * NEG_TOPK;
        #pragma unroll
        for (int q = 0; q < NEG_TOPK; ++q) dst[q] = top[q];
        pos_part[(size_t)row * nch + ch] = pos;
    }
}

// Pass 2: one block per row. Merge nch*10 candidates -> top-10, sum finite;
// reduce pos partials; row_tot[i] = pos + neg.
__global__ __launch_bounds__(256) void cl_pass2(
    const float* __restrict__ part_topk,
    const float* __restrict__ pos_part,
    float* __restrict__ row_tot,
    int nch)
{
    const int i = blockIdx.x;
    const int t = threadIdx.x;
    __shared__ float stop[256][NEG_TOPK];
    __shared__ float stop2[32][NEG_TOPK];
    __shared__ float red[256];

    const int n = nch * NEG_TOPK;
    const float* src = part_topk + (size_t)i * n;
    float top[NEG_TOPK];
    #pragma unroll
    for (int q = 0; q < NEG_TOPK; ++q) top[q] = -INFINITY;
    for (int idx = t; idx < n; idx += 256) topk_ins(top, src[idx]);
    #pragma unroll
    for (int q = 0; q < NEG_TOPK; ++q) stop[t][q] = top[q];

    float pos = 0.0f;
    const float* psrc = pos_part + (size_t)i * nch;
    for (int idx = t; idx < nch; idx += 256) pos += psrc[idx];
    red[t] = pos;
    __syncthreads();

    for (int s2 = 128; s2 >= 1; s2 >>= 1) {
        if (t < s2) red[t] += red[t + s2];
        __syncthreads();
    }

    if (t < 32) {
        float m[NEG_TOPK];
        #pragma unroll
        for (int q = 0; q < NEG_TOPK; ++q) m[q] = -INFINITY;
        for (int l = 0; l < 8; ++l)
            #pragma unroll
            for (int q = 0; q < NEG_TOPK; ++q) topk_ins(m, stop[t * 8 + l][q]);
        #pragma unroll
        for (int q = 0; q < NEG_TOPK; ++q) stop2[t][q] = m[q];
    }
    __syncthreads();

    if (t == 0) {
        float m[NEG_TOPK];
        #pragma unroll
        for (int q = 0; q < NEG_TOPK; ++q) m[q] = -INFINITY;
        for (int l = 0; l < 32; ++l)
            #pragma unroll
            for (int q = 0; q < NEG_TOPK; ++q) topk_ins(m, stop2[l][q]);
        float neg = 0.0f;
        #pragma unroll
        for (int q = 0; q < NEG_TOPK; ++q)
            if (isfinite(m[q])) neg += m[q];
        row_tot[i] = neg + red[0];
    }
}

// Pass 3: mean over rows.
__global__ __launch_bounds__(256) void cl_pass3(
    const float* __restrict__ row_tot, float* __restrict__ out, int Bn)
{
    __shared__ float red[256];
    const int t = threadIdx.x;
    float v = 0.0f;
    for (int idx = t; idx < Bn; idx += 256) v += row_tot[idx];
    red[t] = v;
    __syncthreads();
    for (int s2 = 128; s2 >= 1; s2 >>= 1) {
        if (t < s2) red[t] += red[t + s2];
        __syncthreads();
    }
    if (t == 0) out[0] = red[0] / (float)Bn;
}

extern "C" void kernel_launch(void* const* d_in, const int* in_sizes, int n_in,
                              void* d_out, int out_size, void* d_ws, size_t ws_size,
                              hipStream_t stream)
{
    const float* A    = (const float*)d_in[0];  // inputs_col [B,D]
    const int*   tcol = (const int*)d_in[1];    // targets_col [B]
    const float* Bm   = (const float*)d_in[2];  // inputs_row [M,D]
    const int*   trow = (const int*)d_in[3];    // target_row [M]
    float* out = (float*)d_out;

    const int Bn = in_sizes[1];          // 256
    const int M  = in_sizes[3];          // 65536
    const int D  = in_sizes[0] / Bn;     // 512
    const int numMB = M / MT;            // 512 blocks
    const int nch = numMB * 2;           // 1024 chunks of 64 cols

    char* A_swz = (char*)d_ws;                                    // 256 KB
    float* part_topk = (float*)(A_swz + 8 * ABYTES);              // B*nch*10
    float* pos_part  = part_topk + (size_t)Bn * nch * NEG_TOPK;   // B*nch
    float* row_tot   = pos_part + (size_t)Bn * nch;               // B

    cl_pass0<<<128, 256, 0, stream>>>(A, A_swz, D);
    cl_pass1<<<numMB, 512, 0, stream>>>(A_swz, Bm, tcol, trow,
                                        part_topk, pos_part, D);
    cl_pass2<<<Bn, 256, 0, stream>>>(part_topk, pos_part, row_tot, nch);
    cl_pass3<<<1, 256, 0, stream>>>(row_tot, out, Bn);
}